// Round 5
// baseline (45.425 us; speedup 1.0000x reference)
//
#include <hip/hip_runtime.h>

// Fused: 2x2x2 max-pool (stride 2) + per-channel bias + logsumexp over C=64 + ReLU.
// x = const float* [4,64,64,64,64] (harness upcasts fp16->f32), bias = const float* [64],
// out = float* [4,1,32,32,32]  (dtype forensics: R1..R3 error magnitudes).
//
// R4 passed at 43.4 us = 6.2 TB/s. Fill kernels on the same chip sustain 6.9-7.1
// TB/s at 10% occupancy -> BW headroom exists; chase it with 16 B/lane float4
// loads (2 outputs per lane, half the load instrs + addr VALU, 2x MLP depth).
//
// Decomposition: wave = 64 outputs (2 h' rows x 32 w') for one (n,d').
//   lane&15  -> w' pair (one float4 = both 2-wide W windows)
//   lane>>4&1-> h' row within the pair
//   lane>>5  -> channel half (0..31 / 32..63), merged via __shfl_xor(.,32)
// Output written as coalesced float2 by the chalf==0 half-wave.

__global__ __launch_bounds__(256) void fused_pool_lse_relu(
    const float* __restrict__ x, const float* __restrict__ bias,
    float* __restrict__ out)
{
    __shared__ float s_bias[64];
    if (threadIdx.x < 64) s_bias[threadIdx.x] = bias[threadIdx.x];
    __syncthreads();

    const int lane  = threadIdx.x & 63;
    const int wave  = threadIdx.x >> 6;
    const int chalf = lane >> 5;           // channel half
    const int hbit  = (lane >> 4) & 1;     // which h' row of the pair
    const int wq    = lane & 15;           // w'-pair index (covers w' = 2wq, 2wq+1)

    const int owave = blockIdx.x * 256 + wave * 64;   // multiple of 64
    const int n     = owave >> 15;
    const int dp    = (owave >> 10) & 31;
    const int hpb   = (owave >> 5) & 31;              // even h' base

    // element strides (f32): w:1, h:64, d:4096, c:262144, n:64*262144
    const size_t CS = 262144;
    const float* base = x
        + (size_t)n * (64 * CS)
        + (size_t)(chalf * 32) * CS
        + (size_t)dp * 8192          // 2*dp*4096
        + (size_t)hpb * 128          // 2*hpb*64
        + (size_t)hbit * 128         // 2*64 per h' step
        + (size_t)wq * 4;            // w = 4*wq

    float v0[32], v1[32];
#pragma unroll
    for (int cc = 0; cc < 32; ++cc) {
        const float* p = base + (size_t)cc * CS;
        const float4 a = *(const float4*)(p);          // d0,h0: w 4wq..4wq+3
        const float4 b = *(const float4*)(p + 64);     // d0,h1
        const float4 c = *(const float4*)(p + 4096);   // d1,h0
        const float4 d = *(const float4*)(p + 4160);   // d1,h1
        const float bia = s_bias[chalf * 32 + cc];
        v0[cc] = fmaxf(fmaxf(fmaxf(a.x, a.y), fmaxf(b.x, b.y)),
                       fmaxf(fmaxf(c.x, c.y), fmaxf(d.x, d.y))) + bia;
        v1[cc] = fmaxf(fmaxf(fmaxf(a.z, a.w), fmaxf(b.z, b.w)),
                       fmaxf(fmaxf(c.z, c.w), fmaxf(d.z, d.w))) + bia;
    }

    // two-pass logsumexp per output over this lane's 32 channels
    float m0 = v0[0], m1 = v1[0];
#pragma unroll
    for (int cc = 1; cc < 32; ++cc) { m0 = fmaxf(m0, v0[cc]); m1 = fmaxf(m1, v1[cc]); }
    float s0 = 0.0f, s1 = 0.0f;
#pragma unroll
    for (int cc = 0; cc < 32; ++cc) { s0 += __expf(v0[cc] - m0); s1 += __expf(v1[cc] - m1); }

    // merge channel halves across the lane pair (lane i <-> lane i+32)
    const float m0o = __shfl_xor(m0, 32), s0o = __shfl_xor(s0, 32);
    const float m1o = __shfl_xor(m1, 32), s1o = __shfl_xor(s1, 32);
    const float M0 = fmaxf(m0, m0o), M1 = fmaxf(m1, m1o);
    const float S0 = s0 * __expf(m0 - M0) + s0o * __expf(m0o - M0);
    const float S1 = s1 * __expf(m1 - M1) + s1o * __expf(m1o - M1);
    const float r0 = fmaxf(M0 + __logf(S0), 0.0f);
    const float r1 = fmaxf(M1 + __logf(S1), 0.0f);

    if (chalf == 0) {
        float2 r; r.x = r0; r.y = r1;
        *(float2*)(out + owave + hbit * 32 + wq * 2) = r;
    }
}

extern "C" void kernel_launch(void* const* d_in, const int* in_sizes, int n_in,
                              void* d_out, int out_size, void* d_ws, size_t ws_size,
                              hipStream_t stream)
{
    const float* x    = (const float*)d_in[0];
    const float* bias = (const float*)d_in[1];
    float* out = (float*)d_out;

    // 131072 outputs, 256 per block (4 waves x 64) -> 512 blocks
    const int blocks = out_size / 256;
    fused_pool_lse_relu<<<blocks, 256, 0, stream>>>(x, bias, out);
}

// Round 6
// 43.441 us; speedup vs baseline: 1.0457x; 1.0457x over previous
//
#include <hip/hip_runtime.h>

// Fused: 2x2x2 max-pool (stride 2) + per-channel bias + logsumexp over C=64 + ReLU.
// x = const float* [4,64,64,64,64] (harness upcasts fp16->f32), bias = const float* [64],
// out = float* [4,1,32,32,32].
//
// R4 (float2, 2-way channel split, 16 waves/CU): 43.4 us = 6.2 TB/s.
// R5 (float4, 2 outputs/lane): 45.4 us — REGRESSED; vals[2][32]+float4 temps ->
//   ~200 VGPR -> 2 waves/SIMD; streaming reads need TLP, not width.
// R6: max-TLP variant. Each output owned by a lane QUAD {i,i+16,i+32,i+48},
//   16 channels per member -> vals[16] (~<=64 VGPR -> 8 waves/SIMD), wave = 16
//   outputs, 8192 waves = 32 waves/CU (occupancy cap). float2 loads unchanged.
//   LSE merge: __shfl_xor 16 then 32.

__global__ __launch_bounds__(256) void fused_pool_lse_relu(
    const float* __restrict__ x, const float* __restrict__ bias,
    float* __restrict__ out)
{
    __shared__ float s_bias[64];
    if (threadIdx.x < 64) s_bias[threadIdx.x] = bias[threadIdx.x];
    __syncthreads();

    const int lane = threadIdx.x & 63;
    const int wave = threadIdx.x >> 6;
    const int q    = lane >> 4;          // channel quarter: c = 16q .. 16q+15
    const int t    = lane & 15;          // w' offset within the wave's 16-chunk

    const int o = blockIdx.x * 64 + wave * 16 + t;   // output voxel id

    const int wp = o & 31;          // output w'
    const int hp = (o >> 5) & 31;   // output h'
    const int dp = (o >> 10) & 31;  // output d'
    const int n  = o >> 15;         // batch

    // element strides (f32): w:1, h:64, d:4096, c:262144, n:64*262144
    const size_t CS = 262144;
    const float* base = x
        + (size_t)n * (64 * CS)
        + (size_t)(q * 16) * CS
        + (size_t)dp * 8192        // 2*dp*4096
        + (size_t)hp * 128         // 2*hp*64
        + (size_t)wp * 2;

    float vals[16];
#pragma unroll
    for (int cc = 0; cc < 16; ++cc) {
        const float* p = base + (size_t)cc * CS;
        const float2 a = *(const float2*)(p);          // d0,h0 (w0,w1)
        const float2 b = *(const float2*)(p + 64);     // d0,h1
        const float2 c = *(const float2*)(p + 4096);   // d1,h0
        const float2 d = *(const float2*)(p + 4160);   // d1,h1
        vals[cc] = fmaxf(fmaxf(fmaxf(a.x, a.y), fmaxf(b.x, b.y)),
                         fmaxf(fmaxf(c.x, c.y), fmaxf(d.x, d.y)))
                 + s_bias[q * 16 + cc];
    }

    // two-pass logsumexp over this lane's 16 channels (static indices)
    float m = vals[0];
#pragma unroll
    for (int cc = 1; cc < 16; ++cc) m = fmaxf(m, vals[cc]);
    float s = 0.0f;
#pragma unroll
    for (int cc = 0; cc < 16; ++cc) s += __expf(vals[cc] - m);

    // merge the 4 channel quarters across the lane quad
    {
        const float mo = __shfl_xor(m, 16), so = __shfl_xor(s, 16);
        const float M = fmaxf(m, mo);
        s = s * __expf(m - M) + so * __expf(mo - M);
        m = M;
    }
    {
        const float mo = __shfl_xor(m, 32), so = __shfl_xor(s, 32);
        const float M = fmaxf(m, mo);
        s = s * __expf(m - M) + so * __expf(mo - M);
        m = M;
    }

    if (q == 0) out[o] = fmaxf(m + __logf(s), 0.0f);   // ReLU
}

extern "C" void kernel_launch(void* const* d_in, const int* in_sizes, int n_in,
                              void* d_out, int out_size, void* d_ws, size_t ws_size,
                              hipStream_t stream)
{
    const float* x    = (const float*)d_in[0];
    const float* bias = (const float*)d_in[1];
    float* out = (float*)d_out;

    // 131072 outputs, 64 per block (4 waves x 16) -> 2048 blocks
    const int blocks = out_size / 64;
    fused_pool_lse_relu<<<blocks, 256, 0, stream>>>(x, bias, out);
}